// Round 1
// baseline (969.363 us; speedup 1.0000x reference)
//
#include <hip/hip_runtime.h>

#define M_DIM 8192
#define K_DIM 4096
#define N_DIM 11008
#define BM 128
#define BN 128
#define BK 64
#define TILES_N (N_DIM / BN)   // 86
#define TILES_M (M_DIM / BM)   // 64

typedef __attribute__((ext_vector_type(8))) short bf16x8;
typedef __attribute__((ext_vector_type(4))) float f32x4;
typedef __attribute__((ext_vector_type(8))) unsigned short u16x8;

__device__ __forceinline__ unsigned short f2bf_rne(float f) {
    unsigned int u = __float_as_uint(f);
    unsigned int r = (u + 0x7FFFu + ((u >> 16) & 1u)) >> 16;
    return (unsigned short)r;
}

__device__ __forceinline__ void gload_lds16(const void* g, void* l) {
    __builtin_amdgcn_global_load_lds(
        (const __attribute__((address_space(1))) void*)g,
        (__attribute__((address_space(3))) void*)l, 16, 0, 0);
}

// ---------------- x: fp32 -> bf16 (8 elems / thread) ----------------
__global__ __launch_bounds__(256) void cast_x_kernel(const float* __restrict__ x,
                                                     unsigned short* __restrict__ xb) {
    size_t t = (size_t)blockIdx.x * 256 + threadIdx.x;
    const float4* p = reinterpret_cast<const float4*>(x) + 2 * t;
    float4 a = p[0];
    float4 b = p[1];
    u16x8 o;
    o[0] = f2bf_rne(a.x); o[1] = f2bf_rne(a.y); o[2] = f2bf_rne(a.z); o[3] = f2bf_rne(a.w);
    o[4] = f2bf_rne(b.x); o[5] = f2bf_rne(b.y); o[6] = f2bf_rne(b.z); o[7] = f2bf_rne(b.w);
    *reinterpret_cast<u16x8*>(xb + 8 * t) = o;
}

// ------- weight: per-128-group absmax scale, sign*scale -> bf16 -------
// 32 lanes per group, 4 floats/lane (float4).
__global__ __launch_bounds__(256) void binarize_w_kernel(const float* __restrict__ w,
                                                         unsigned short* __restrict__ weff) {
    size_t t = (size_t)blockIdx.x * 256 + threadIdx.x;
    size_t group = t >> 5;
    int l32 = (int)(t & 31);
    const float4* src = reinterpret_cast<const float4*>(w + group * 128) + l32;
    float4 v = *src;
    float amax = fmaxf(fmaxf(fabsf(v.x), fabsf(v.y)), fmaxf(fabsf(v.z), fabsf(v.w)));
#pragma unroll
    for (int off = 16; off >= 1; off >>= 1)
        amax = fmaxf(amax, __shfl_xor(amax, off));   // stays within 32-lane half
    float scale = fmaxf(amax, 1e-8f);
    unsigned short pb = f2bf_rne(scale);
    unsigned short nb = (unsigned short)(pb | 0x8000u);
    ushort4 o;
    o.x = (v.x == 0.0f) ? (unsigned short)0 : ((v.x > 0.0f) ? pb : nb);
    o.y = (v.y == 0.0f) ? (unsigned short)0 : ((v.y > 0.0f) ? pb : nb);
    o.z = (v.z == 0.0f) ? (unsigned short)0 : ((v.z > 0.0f) ? pb : nb);
    o.w = (v.w == 0.0f) ? (unsigned short)0 : ((v.w > 0.0f) ? pb : nb);
    *reinterpret_cast<ushort4*>(weff + group * 128 + (size_t)l32 * 4) = o;
}

// ---------------- GEMM: C[M][N] = Xb[M][K] * Weff[N][K]^T ----------------
// 128x128 tile, BK=64, 4 waves (2x2), each wave 64x64 via 4x4 frags of
// mfma_f32_16x16x32_bf16. global_load_lds width=16, linear LDS, 2 barriers/K-step.
__global__ __launch_bounds__(256, 2) void gemm_bin_kernel(
        const unsigned short* __restrict__ A,   // Xb  [M][K] bf16
        const unsigned short* __restrict__ B,   // Weff[N][K] bf16
        float* __restrict__ C) {
    __shared__ unsigned short As[BM * BK];   // [128][64] linear
    __shared__ unsigned short Bs[BN * BK];

    int bid = blockIdx.x;
    // XCD-aware bijective swizzle: grid = 5504 = 8 * 688
    int swz = (bid & 7) * ((TILES_M * TILES_N) >> 3) + (bid >> 3);
    int tm = swz / TILES_N;
    int tn = swz % TILES_N;

    int t = threadIdx.x;
    int wave = t >> 6;
    int lane = t & 63;
    int wr = (wave >> 1) * 64;   // wave row offset within tile
    int wc = (wave & 1) * 64;    // wave col offset within tile
    int l15 = lane & 15;
    int l4 = lane >> 4;          // 0..3

    f32x4 acc[4][4] = {};

    const unsigned short* Ab = A + (size_t)tm * BM * K_DIM;
    const unsigned short* Bb = B + (size_t)tn * BN * K_DIM;

    int srow = t >> 3;           // 0..31 (+32 per round)
    int scol = (t & 7) * 8;      // element col, 16B runs

    for (int kt = 0; kt < K_DIM; kt += BK) {
#pragma unroll
        for (int r = 0; r < 4; ++r) {
            int row = srow + r * 32;
            gload_lds16(Ab + (size_t)row * K_DIM + kt + scol, &As[row * BK + scol]);
            gload_lds16(Bb + (size_t)row * K_DIM + kt + scol, &Bs[row * BK + scol]);
        }
        __syncthreads();
#pragma unroll
        for (int ks = 0; ks < 2; ++ks) {
            bf16x8 af[4], bf[4];
#pragma unroll
            for (int i = 0; i < 4; ++i)
                af[i] = *reinterpret_cast<const bf16x8*>(&As[(wr + i * 16 + l15) * BK + ks * 32 + l4 * 8]);
#pragma unroll
            for (int j = 0; j < 4; ++j)
                bf[j] = *reinterpret_cast<const bf16x8*>(&Bs[(wc + j * 16 + l15) * BK + ks * 32 + l4 * 8]);
#pragma unroll
            for (int i = 0; i < 4; ++i)
#pragma unroll
                for (int j = 0; j < 4; ++j)
                    acc[i][j] = __builtin_amdgcn_mfma_f32_16x16x32_bf16(af[i], bf[j], acc[i][j], 0, 0, 0);
        }
        __syncthreads();
    }

    // Epilogue: C/D layout col=lane&15, row=(lane>>4)*4+reg
#pragma unroll
    for (int i = 0; i < 4; ++i) {
        int row0 = tm * BM + wr + i * 16 + l4 * 4;
#pragma unroll
        for (int j = 0; j < 4; ++j) {
            int col = tn * BN + wc + j * 16 + l15;
#pragma unroll
            for (int r = 0; r < 4; ++r) {
                C[(size_t)(row0 + r) * N_DIM + col] = acc[i][j][r];
            }
        }
    }
}

extern "C" void kernel_launch(void* const* d_in, const int* in_sizes, int n_in,
                              void* d_out, int out_size, void* d_ws, size_t ws_size,
                              hipStream_t stream) {
    const float* x = (const float*)d_in[0];       // [4,2048,4096] fp32
    const float* w = (const float*)d_in[1];       // [11008,4096] fp32
    float* out = (float*)d_out;                   // [4,2048,11008] fp32

    unsigned short* xb = (unsigned short*)d_ws;                               // 64 MiB
    unsigned short* weff = (unsigned short*)((char*)d_ws + (size_t)M_DIM * K_DIM * 2); // 86 MiB

    cast_x_kernel<<<(M_DIM * K_DIM / 8) / 256, 256, 0, stream>>>(x, xb);          // 16384 blocks
    binarize_w_kernel<<<(N_DIM * K_DIM / 4) / 256, 256, 0, stream>>>(w, weff);    // 44032 blocks
    gemm_bin_kernel<<<TILES_M * TILES_N, 256, 0, stream>>>(xb, weff, out);        // 5504 blocks
}

// Round 2
// 733.549 us; speedup vs baseline: 1.3215x; 1.3215x over previous
//
#include <hip/hip_runtime.h>

#define M_DIM 8192
#define K_DIM 4096
#define N_DIM 11008
#define BM 256
#define BN 256
#define BK 64
#define TILES_M (M_DIM / BM)     // 32
#define TILES_N (N_DIM / BN)     // 43
#define NT (K_DIM / BK)          // 64
#define NWG (TILES_M * TILES_N)  // 1376 = 8 * 172

typedef __attribute__((ext_vector_type(8))) short bf16x8;
typedef __attribute__((ext_vector_type(4))) float f32x4;
typedef __attribute__((ext_vector_type(8))) unsigned short u16x8;

__device__ __forceinline__ unsigned short f2bf_rne(float f) {
    unsigned int u = __float_as_uint(f);
    unsigned int r = (u + 0x7FFFu + ((u >> 16) & 1u)) >> 16;
    return (unsigned short)r;
}

__device__ __forceinline__ void gload_lds16(const void* g, void* l) {
    __builtin_amdgcn_global_load_lds(
        (const __attribute__((address_space(1))) void*)g,
        (__attribute__((address_space(3))) void*)l, 16, 0, 0);
}

// ---------------- x: fp32 -> bf16 (8 elems / thread) ----------------
__global__ __launch_bounds__(256) void cast_x_kernel(const float* __restrict__ x,
                                                     unsigned short* __restrict__ xb) {
    size_t t = (size_t)blockIdx.x * 256 + threadIdx.x;
    const float4* p = reinterpret_cast<const float4*>(x) + 2 * t;
    float4 a = p[0];
    float4 b = p[1];
    u16x8 o;
    o[0] = f2bf_rne(a.x); o[1] = f2bf_rne(a.y); o[2] = f2bf_rne(a.z); o[3] = f2bf_rne(a.w);
    o[4] = f2bf_rne(b.x); o[5] = f2bf_rne(b.y); o[6] = f2bf_rne(b.z); o[7] = f2bf_rne(b.w);
    *reinterpret_cast<u16x8*>(xb + 8 * t) = o;
}

// ------- weight: per-128-group absmax scale, sign*scale -> bf16 -------
__global__ __launch_bounds__(256) void binarize_w_kernel(const float* __restrict__ w,
                                                         unsigned short* __restrict__ weff) {
    size_t t = (size_t)blockIdx.x * 256 + threadIdx.x;
    size_t group = t >> 5;
    int l32 = (int)(t & 31);
    const float4* src = reinterpret_cast<const float4*>(w + group * 128) + l32;
    float4 v = *src;
    float amax = fmaxf(fmaxf(fabsf(v.x), fabsf(v.y)), fmaxf(fabsf(v.z), fabsf(v.w)));
#pragma unroll
    for (int off = 16; off >= 1; off >>= 1)
        amax = fmaxf(amax, __shfl_xor(amax, off));
    float scale = fmaxf(amax, 1e-8f);
    unsigned short pb = f2bf_rne(scale);
    unsigned short nb = (unsigned short)(pb | 0x8000u);
    ushort4 o;
    o.x = (v.x == 0.0f) ? (unsigned short)0 : ((v.x > 0.0f) ? pb : nb);
    o.y = (v.y == 0.0f) ? (unsigned short)0 : ((v.y > 0.0f) ? pb : nb);
    o.z = (v.z == 0.0f) ? (unsigned short)0 : ((v.z > 0.0f) ? pb : nb);
    o.w = (v.w == 0.0f) ? (unsigned short)0 : ((v.w > 0.0f) ? pb : nb);
    *reinterpret_cast<ushort4*>(weff + group * 128 + (size_t)l32 * 4) = o;
}

// ---------------- GEMM: C[M][N] = Xb[M][K] * Weff[N][K]^T ----------------
// 256x256 tile, BK=64, 8 waves (2Mx4N), 8-phase schedule w/ counted vmcnt,
// st-swizzled LDS (slot ^= row&7, 16B granules), setprio around MFMA cluster.
__global__ __launch_bounds__(512, 2) void gemm_bin_kernel(
        const unsigned short* __restrict__ A,   // Xb  [M][K] bf16
        const unsigned short* __restrict__ B,   // Weff[N][K] bf16
        float* __restrict__ C) {
    // [buf][A=0/B=1][half][128*64 shorts] = 128 KiB
    __shared__ unsigned short lds[2][2][2][8192];

    const int bid = blockIdx.x;
    const int swz = (bid & 7) * (NWG / 8) + (bid >> 3);   // bijective: NWG % 8 == 0
    const int tm = swz / TILES_N;
    const int tn = swz % TILES_N;

    const int tid = threadIdx.x;
    const int wave = tid >> 6;
    const int lane = tid & 63;
    const int wm = wave >> 2;      // 0..1 -> A half
    const int wn = wave & 3;       // 0..3 -> B half = wn>>1, sub-block = wn&1
    const int l15 = lane & 15;
    const int l4  = lane >> 4;

    // ---- staging addressing: linear LDS dest, pre-swizzled global source ----
    const int srow  = tid >> 3;                  // 0..63 (chunk adds +64)
    const int gslot = (tid & 7) ^ (srow & 7);    // swizzle is chunk-invariant
    const unsigned short* Asrc = A + (size_t)(tm * BM + srow) * K_DIM + gslot * 8;
    const unsigned short* Bsrc = B + (size_t)(tn * BN + srow) * K_DIM + gslot * 8;

    auto stageA = [&](int buf, int half, int kt) {
        const unsigned short* s = Asrc + (size_t)(half * 128) * K_DIM + kt;
        unsigned short* d = &lds[buf][0][half][tid * 8];
        gload_lds16(s, d);
        gload_lds16(s + (size_t)64 * K_DIM, d + 4096);
    };
    auto stageB = [&](int buf, int half, int kt) {
        const unsigned short* s = Bsrc + (size_t)(half * 128) * K_DIM + kt;
        unsigned short* d = &lds[buf][1][half][tid * 8];
        gload_lds16(s, d);
        gload_lds16(s + (size_t)64 * K_DIM, d + 4096);
    };
    // swizzled fragment read: row-major [128][64] + (slot ^= row&7) on 16B slots
    auto readfrag = [&](const unsigned short* base, int rowl, int ks) -> bf16x8 {
        return *reinterpret_cast<const bf16x8*>(
            &base[rowl * 64 + (((ks * 4 + l4) ^ (rowl & 7)) * 8)]);
    };

    f32x4 acc[8][4] = {};
    bf16x8 bf[4][2];

    // ---- prologue: tile0 {A0,A1,B0,B1} + tile1 {B0,B1}; keep B(t1) in flight ----
    stageA(0, 0, 0); stageA(0, 1, 0);
    stageB(0, 0, 0); stageB(0, 1, 0);
    stageB(1, 0, BK); stageB(1, 1, BK);
    asm volatile("s_waitcnt vmcnt(4)" ::: "memory");
    __builtin_amdgcn_s_barrier();

    for (int t = 0; t < NT; ++t) {
        const int c = t & 1;
        const unsigned short* Ah = &lds[c][0][wm][0];
        const unsigned short* Bh = &lds[c][1][wn >> 1][0];
        const int brow0 = (wn & 1) * 64;

#pragma unroll
        for (int q = 0; q < 4; ++q) {
            bf16x8 af[2][2];
            if (q == 0) {
#pragma unroll
                for (int j = 0; j < 4; ++j)
#pragma unroll
                    for (int ks = 0; ks < 2; ++ks)
                        bf[j][ks] = readfrag(Bh, brow0 + j * 16 + l15, ks);
            }
#pragma unroll
            for (int r = 0; r < 2; ++r)
#pragma unroll
                for (int ks = 0; ks < 2; ++ks)
                    af[r][ks] = readfrag(Ah, (2 * q + r) * 16 + l15, ks);

            // stage schedule: A(t+1) into other buf (freed at group start);
            // B(t+2) into CURRENT buf's B region (freed after phase 1).
            if (q == 0 && t + 1 < NT) stageA(c ^ 1, 0, (t + 1) * BK);
            if (q == 1 && t + 1 < NT) stageA(c ^ 1, 1, (t + 1) * BK);
            if (q == 2 && t + 2 < NT) stageB(c, 0, (t + 2) * BK);
            if (q == 3 && t + 2 < NT) stageB(c, 1, (t + 2) * BK);

            __builtin_amdgcn_s_barrier();
            asm volatile("s_waitcnt lgkmcnt(0)" ::: "memory");
            __builtin_amdgcn_s_setprio(1);
#pragma unroll
            for (int ks = 0; ks < 2; ++ks)
#pragma unroll
                for (int r = 0; r < 2; ++r)
#pragma unroll
                    for (int j = 0; j < 4; ++j)
                        acc[2 * q + r][j] = __builtin_amdgcn_mfma_f32_16x16x32_bf16(
                            af[r][ks], bf[j][ks], acc[2 * q + r][j], 0, 0, 0);
            __builtin_amdgcn_s_setprio(0);
            if (q == 3) {
                if (t < NT - 2) asm volatile("s_waitcnt vmcnt(4)" ::: "memory");
                else            asm volatile("s_waitcnt vmcnt(0)" ::: "memory");
            }
            __builtin_amdgcn_s_barrier();
        }
    }

    // ---- epilogue: C/D layout col=lane&15, row=(lane>>4)*4+reg ----
    const size_t crow0 = (size_t)tm * BM + wm * 128 + l4 * 4;
    const int ccol0 = tn * BN + wn * 64 + l15;
#pragma unroll
    for (int i = 0; i < 8; ++i) {
#pragma unroll
        for (int j = 0; j < 4; ++j) {
            float* cp = C + (crow0 + i * 16) * N_DIM + ccol0 + j * 16;
#pragma unroll
            for (int r = 0; r < 4; ++r)
                cp[(size_t)r * N_DIM] = acc[i][j][r];
        }
    }
}

extern "C" void kernel_launch(void* const* d_in, const int* in_sizes, int n_in,
                              void* d_out, int out_size, void* d_ws, size_t ws_size,
                              hipStream_t stream) {
    const float* x = (const float*)d_in[0];       // [4,2048,4096] fp32
    const float* w = (const float*)d_in[1];       // [11008,4096] fp32
    float* out = (float*)d_out;                   // [4,2048,11008] fp32

    unsigned short* xb = (unsigned short*)d_ws;                                        // 64 MiB
    unsigned short* weff = (unsigned short*)((char*)d_ws + (size_t)M_DIM * K_DIM * 2); // 86 MiB

    cast_x_kernel<<<(M_DIM * K_DIM / 8) / 256, 256, 0, stream>>>(x, xb);
    binarize_w_kernel<<<(N_DIM * K_DIM / 4) / 256, 256, 0, stream>>>(w, weff);
    gemm_bin_kernel<<<NWG, 512, 0, stream>>>(xb, weff, out);
}